// Round 1
// baseline (42.591 us; speedup 1.0000x reference)
//
#include <hip/hip_runtime.h>

#define DEV __device__ __forceinline__

// ---------- complex pair primitives (all fp32) ----------

DEV void rx_pair(float& r0, float& i0, float& r1, float& i1, float c, float s) {
    // a0' = c a0 - i s a1 ; a1' = c a1 - i s a0
    float nr0 = fmaf(c, r0,  s * i1);
    float ni0 = fmaf(c, i0, -s * r1);
    float nr1 = fmaf(c, r1,  s * i0);
    float ni1 = fmaf(c, i1, -s * r0);
    r0 = nr0; i0 = ni0; r1 = nr1; i1 = ni1;
}

DEV void ry_pair(float& r0, float& i0, float& r1, float& i1, float c, float s) {
    // a0' = c a0 - s a1 ; a1' = s a0 + c a1
    float nr0 = fmaf(c, r0, -s * r1);
    float ni0 = fmaf(c, i0, -s * i1);
    float nr1 = fmaf(c, r1,  s * r0);
    float ni1 = fmaf(c, i1,  s * i0);
    r0 = nr0; i0 = ni0; r1 = nr1; i1 = ni1;
}

DEV void rz_amp(float& r, float& i, float c, float ss) {
    // multiply by (c + i*ss)   [ss = sgn * s]
    float nr = fmaf(c, r, -ss * i);
    float ni = fmaf(c, i,  ss * r);
    r = nr; i = ni;
}

// ---------- gate application: bit B of flat index (B=7-qubit) ----------
// layout: amplitude idx = k*64 + lane; bits 0..5 = lane bits, 6 = k bit0, 7 = k bit1

template<int B>
DEV void apply_rx(float (&re)[4], float (&im)[4], int lane, float c, float s) {
    if constexpr (B == 7) {
        rx_pair(re[0], im[0], re[2], im[2], c, s);
        rx_pair(re[1], im[1], re[3], im[3], c, s);
    } else if constexpr (B == 6) {
        rx_pair(re[0], im[0], re[1], im[1], c, s);
        rx_pair(re[2], im[2], re[3], im[3], c, s);
    } else {
#pragma unroll
        for (int k = 0; k < 4; ++k) {
            float pr = __shfl_xor(re[k], 1 << B, 64);
            float pi = __shfl_xor(im[k], 1 << B, 64);
            re[k] = fmaf(c, re[k],  s * pi);   // RX is symmetric: no hi/lo branch
            im[k] = fmaf(c, im[k], -s * pr);
        }
    }
}

template<int B>
DEV void apply_ry(float (&re)[4], float (&im)[4], int lane, float c, float s) {
    if constexpr (B == 7) {
        ry_pair(re[0], im[0], re[2], im[2], c, s);
        ry_pair(re[1], im[1], re[3], im[3], c, s);
    } else if constexpr (B == 6) {
        ry_pair(re[0], im[0], re[1], im[1], c, s);
        ry_pair(re[2], im[2], re[3], im[3], c, s);
    } else {
        float ssel = ((lane >> B) & 1) ? s : -s;   // lo: c a - s p ; hi: c a + s p
#pragma unroll
        for (int k = 0; k < 4; ++k) {
            float pr = __shfl_xor(re[k], 1 << B, 64);
            float pi = __shfl_xor(im[k], 1 << B, 64);
            re[k] = fmaf(c, re[k], ssel * pr);
            im[k] = fmaf(c, im[k], ssel * pi);
        }
    }
}

template<int B>
DEV void apply_rz(float (&re)[4], float (&im)[4], int lane, float c, float s) {
    // bit=0: *(c - i s) ; bit=1: *(c + i s)  -- diagonal, zero shuffles
    if constexpr (B == 7) {
        rz_amp(re[0], im[0], c, -s); rz_amp(re[1], im[1], c, -s);
        rz_amp(re[2], im[2], c,  s); rz_amp(re[3], im[3], c,  s);
    } else if constexpr (B == 6) {
        rz_amp(re[0], im[0], c, -s); rz_amp(re[1], im[1], c,  s);
        rz_amp(re[2], im[2], c, -s); rz_amp(re[3], im[3], c,  s);
    } else {
        float ss = ((lane >> B) & 1) ? s : -s;
#pragma unroll
        for (int k = 0; k < 4; ++k) rz_amp(re[k], im[k], c, ss);
    }
}

template<int BC, int BT>
DEV void apply_cnot(float (&re)[4], float (&im)[4], int lane) {
    if constexpr (BC == 7 && BT == 6) {
        // ctrl = k bit1, tgt = k bit0: swap k=2 <-> k=3 (register rename)
        float tr = re[2], ti = im[2];
        re[2] = re[3]; im[2] = im[3];
        re[3] = tr;    im[3] = ti;
    } else if constexpr (BC == 6) {
        // ctrl = k bit0 (k=1,3 always control-on): unconditional swap across lane bit BT
        re[1] = __shfl_xor(re[1], 1 << BT, 64); im[1] = __shfl_xor(im[1], 1 << BT, 64);
        re[3] = __shfl_xor(re[3], 1 << BT, 64); im[3] = __shfl_xor(im[3], 1 << BT, 64);
    } else {
        bool ctrl = (lane >> BC) & 1;
#pragma unroll
        for (int k = 0; k < 4; ++k) {
            float pr = __shfl_xor(re[k], 1 << BT, 64);
            float pi = __shfl_xor(im[k], 1 << BT, 64);
            re[k] = ctrl ? pr : re[k];
            im[k] = ctrl ? pi : im[k];
        }
    }
}

// ---------- prep: cos/sin of 48 shared params into ws ----------

__global__ void qa_prep(const float* __restrict__ params, float* __restrict__ gc, int n) {
    int t = blockIdx.x * blockDim.x + threadIdx.x;
    if (t < n) {
        float th = params[t] * 0.5f;
        gc[2 * t]     = cosf(th);
        gc[2 * t + 1] = sinf(th);
    }
}

// ---------- main: one wave per batch element ----------

__global__ __launch_bounds__(256) void qa_sim(
    const float* __restrict__ x, const float* __restrict__ gc,
    float* __restrict__ out, int batch)
{
    int tid  = blockIdx.x * 256 + threadIdx.x;
    int b    = tid >> 6;
    int lane = threadIdx.x & 63;
    if (b >= batch) return;

    float re[4], im[4];
    re[0] = (lane == 0) ? 1.f : 0.f;
    re[1] = re[2] = re[3] = 0.f;
    im[0] = im[1] = im[2] = im[3] = 0.f;

    const float* xb = x + b * 8;

    // ---- data encoding: RX(x[b,i]) on qubit i (bit 7-i) ----
#define ENC(i) { float s_, c_; __sincosf(xb[i] * 0.5f, &s_, &c_); \
                 apply_rx<7 - (i)>(re, im, lane, c_, s_); }
    ENC(0) ENC(1) ENC(2) ENC(3) ENC(4) ENC(5) ENC(6) ENC(7)
#undef ENC

    // ---- variational layers ----
    // params[l][i][g], g in {RY, RZ, RX}; gc holds (cos,sin) pairs
#define VQ(l, i) { const float* g = gc + 2 * ((l) * 24 + (i) * 3); \
                   apply_ry<7 - (i)>(re, im, lane, g[0], g[1]);    \
                   apply_rz<7 - (i)>(re, im, lane, g[2], g[3]); }
#define CN(i)    apply_cnot<7 - (i), 6 - (i)>(re, im, lane);
#define RXQ(l,i) { const float* g = gc + 2 * ((l) * 24 + (i) * 3 + 2); \
                   apply_rx<7 - (i)>(re, im, lane, g[0], g[1]); }
#define LAYER(l) \
    VQ(l,0) CN(0) VQ(l,1) CN(1) VQ(l,2) CN(2) VQ(l,3) CN(3) \
    VQ(l,4) CN(4) VQ(l,5) CN(5) VQ(l,6) CN(6) VQ(l,7)       \
    RXQ(l,0) RXQ(l,1) RXQ(l,2) RXQ(l,3) RXQ(l,4) RXQ(l,5) RXQ(l,6) RXQ(l,7)

    LAYER(0)
    LAYER(1)
#undef LAYER
#undef RXQ
#undef CN
#undef VQ

    // ---- <Z_i> readout ----
    float p0 = fmaf(re[0], re[0], im[0] * im[0]);
    float p1 = fmaf(re[1], re[1], im[1] * im[1]);
    float p2 = fmaf(re[2], re[2], im[2] * im[2]);
    float p3 = fmaf(re[3], re[3], im[3] * im[3]);

    float z[8];
    z[0] = (p0 + p1) - (p2 + p3);            // qubit0 = bit7 = k bit1
    z[1] = (p0 - p1) + (p2 - p3);            // qubit1 = bit6 = k bit0
    float pt = (p0 + p1) + (p2 + p3);
#pragma unroll
    for (int i = 2; i < 8; ++i) {            // qubit i = lane bit (7-i)
        int bb = 7 - i;
        z[i] = ((lane >> bb) & 1) ? -pt : pt;
    }

#pragma unroll
    for (int d = 1; d < 64; d <<= 1) {
#pragma unroll
        for (int i = 0; i < 8; ++i) z[i] += __shfl_xor(z[i], d, 64);
    }

    if (lane == 0) {
        float4* o = (float4*)(out + b * 8);
        o[0] = make_float4(z[0], z[1], z[2], z[3]);
        o[1] = make_float4(z[4], z[5], z[6], z[7]);
    }
}

extern "C" void kernel_launch(void* const* d_in, const int* in_sizes, int n_in,
                              void* d_out, int out_size, void* d_ws, size_t ws_size,
                              hipStream_t stream) {
    const float* x      = (const float*)d_in[0];   // (BATCH, 8)
    const float* params = (const float*)d_in[1];   // (2, 8, 3)
    float* out = (float*)d_out;
    float* gc  = (float*)d_ws;                     // 96 floats of (cos,sin)

    int batch   = in_sizes[0] / 8;
    int nparams = in_sizes[1];                     // 48

    qa_prep<<<1, 64, 0, stream>>>(params, gc, nparams);

    int blocks = (batch * 64 + 255) / 256;
    qa_sim<<<blocks, 256, 0, stream>>>(x, gc, out, batch);
}

// Round 2
// 30.804 us; speedup vs baseline: 1.3826x; 1.3826x over previous
//
#include <hip/hip_runtime.h>

#define DEV __device__ __forceinline__

typedef unsigned u32;
typedef u32 u32x2 __attribute__((ext_vector_type(2)));

// ---------- cross-lane xor-shuffle, pipe-optimized ----------
// B = lane-bit distance. xor1/2/8 -> DPP (VALU pipe). xor4/16 -> ds_swizzle
// imm BitMode (DS pipe, no addr VGPR). xor32 -> v_permlane32_swap (VALU) with
// runtime-probed result ordering (convention-independent).

template<int B>
DEV float lshfl(float x, bool pick_x) {
    int xi = __float_as_int(x);
    if constexpr (B == 0) {        // quad_perm [1,0,3,2]
        return __int_as_float(__builtin_amdgcn_update_dpp(xi, xi, 0xB1, 0xF, 0xF, false));
    } else if constexpr (B == 1) { // quad_perm [2,3,0,1]
        return __int_as_float(__builtin_amdgcn_update_dpp(xi, xi, 0x4E, 0xF, 0xF, false));
    } else if constexpr (B == 2) { // ds_swizzle xor4:  (4<<10)|0x1F
        return __int_as_float(__builtin_amdgcn_ds_swizzle(xi, 0x101F));
    } else if constexpr (B == 3) { // row_ror:8 == xor8 within 16-lane row
        return __int_as_float(__builtin_amdgcn_update_dpp(xi, xi, 0x128, 0xF, 0xF, false));
    } else if constexpr (B == 4) { // ds_swizzle xor16: (16<<10)|0x1F
        return __int_as_float(__builtin_amdgcn_ds_swizzle(xi, 0x401F));
    } else {                       // xor32: permlane32_swap + select
        u32x2 r = __builtin_amdgcn_permlane32_swap((u32)xi, (u32)xi, false, false);
        return __int_as_float((int)(pick_x ? r.x : r.y));
    }
}

// One-time probe: both swap conventions produce {low-bcast, high-bcast} in
// some order; determine per-lane which element holds the OTHER half's value.
DEV bool probe_pick_x(int lane) {
    u32 p = (u32)((lane >> 5) & 1);
    u32x2 r = __builtin_amdgcn_permlane32_swap(p, p, false, false);
    return r.x == (p ^ 1u);
}

// ---------- complex pair primitives (all fp32) ----------

DEV void rx_pair(float& r0, float& i0, float& r1, float& i1, float c, float s) {
    float nr0 = fmaf(c, r0,  s * i1);
    float ni0 = fmaf(c, i0, -s * r1);
    float nr1 = fmaf(c, r1,  s * i0);
    float ni1 = fmaf(c, i1, -s * r0);
    r0 = nr0; i0 = ni0; r1 = nr1; i1 = ni1;
}

DEV void ry_pair(float& r0, float& i0, float& r1, float& i1, float c, float s) {
    float nr0 = fmaf(c, r0, -s * r1);
    float ni0 = fmaf(c, i0, -s * i1);
    float nr1 = fmaf(c, r1,  s * r0);
    float ni1 = fmaf(c, i1,  s * i0);
    r0 = nr0; i0 = ni0; r1 = nr1; i1 = ni1;
}

DEV void rz_amp(float& r, float& i, float c, float ss) {
    float nr = fmaf(c, r, -ss * i);
    float ni = fmaf(c, i,  ss * r);
    r = nr; i = ni;
}

// ---------- gate application: bit B of flat index (B = 7 - qubit) ----------
// layout: amplitude idx = k*64 + lane; bits 0..5 = lane bits, 6 = k bit0, 7 = k bit1

template<int B>
DEV void apply_rx(float (&re)[4], float (&im)[4], int lane, bool px, float c, float s) {
    if constexpr (B == 7) {
        rx_pair(re[0], im[0], re[2], im[2], c, s);
        rx_pair(re[1], im[1], re[3], im[3], c, s);
    } else if constexpr (B == 6) {
        rx_pair(re[0], im[0], re[1], im[1], c, s);
        rx_pair(re[2], im[2], re[3], im[3], c, s);
    } else {
#pragma unroll
        for (int k = 0; k < 4; ++k) {
            float pr = lshfl<B>(re[k], px);
            float pi = lshfl<B>(im[k], px);
            re[k] = fmaf(c, re[k],  s * pi);   // RX symmetric: no hi/lo branch
            im[k] = fmaf(c, im[k], -s * pr);
        }
    }
}

template<int B>
DEV void apply_ry(float (&re)[4], float (&im)[4], int lane, bool px, float c, float s) {
    if constexpr (B == 7) {
        ry_pair(re[0], im[0], re[2], im[2], c, s);
        ry_pair(re[1], im[1], re[3], im[3], c, s);
    } else if constexpr (B == 6) {
        ry_pair(re[0], im[0], re[1], im[1], c, s);
        ry_pair(re[2], im[2], re[3], im[3], c, s);
    } else {
        float ssel = ((lane >> B) & 1) ? s : -s;
#pragma unroll
        for (int k = 0; k < 4; ++k) {
            float pr = lshfl<B>(re[k], px);
            float pi = lshfl<B>(im[k], px);
            re[k] = fmaf(c, re[k], ssel * pr);
            im[k] = fmaf(c, im[k], ssel * pi);
        }
    }
}

template<int B>
DEV void apply_rz(float (&re)[4], float (&im)[4], int lane, float c, float s) {
    if constexpr (B == 7) {
        rz_amp(re[0], im[0], c, -s); rz_amp(re[1], im[1], c, -s);
        rz_amp(re[2], im[2], c,  s); rz_amp(re[3], im[3], c,  s);
    } else if constexpr (B == 6) {
        rz_amp(re[0], im[0], c, -s); rz_amp(re[1], im[1], c,  s);
        rz_amp(re[2], im[2], c, -s); rz_amp(re[3], im[3], c,  s);
    } else {
        float ss = ((lane >> B) & 1) ? s : -s;
#pragma unroll
        for (int k = 0; k < 4; ++k) rz_amp(re[k], im[k], c, ss);
    }
}

template<int BC, int BT>
DEV void apply_cnot(float (&re)[4], float (&im)[4], int lane, bool px) {
    if constexpr (BC == 7 && BT == 6) {
        float tr = re[2], ti = im[2];
        re[2] = re[3]; im[2] = im[3];
        re[3] = tr;    im[3] = ti;
    } else if constexpr (BC == 6) {
        // ctrl = k bit0 (k=1,3 always on): unconditional swap across lane bit BT
        re[1] = lshfl<BT>(re[1], px); im[1] = lshfl<BT>(im[1], px);
        re[3] = lshfl<BT>(re[3], px); im[3] = lshfl<BT>(im[3], px);
    } else {
        bool ctrl = (lane >> BC) & 1;
#pragma unroll
        for (int k = 0; k < 4; ++k) {
            float pr = lshfl<BT>(re[k], px);
            float pi = lshfl<BT>(im[k], px);
            re[k] = ctrl ? pr : re[k];
            im[k] = ctrl ? pi : im[k];
        }
    }
}

// ---------- prep: cos/sin of 48 shared params into ws ----------

__global__ void qa_prep(const float* __restrict__ params, float* __restrict__ gc, int n) {
    int t = blockIdx.x * blockDim.x + threadIdx.x;
    if (t < n) {
        float th = params[t] * 0.5f;
        gc[2 * t]     = cosf(th);
        gc[2 * t + 1] = sinf(th);
    }
}

// ---------- main: one wave per batch element ----------

__global__ __launch_bounds__(256) void qa_sim(
    const float* __restrict__ x, const float* __restrict__ gc,
    float* __restrict__ out, int batch)
{
    int tid  = blockIdx.x * 256 + threadIdx.x;
    int b    = tid >> 6;
    int lane = threadIdx.x & 63;
    if (b >= batch) return;

    bool px = probe_pick_x(lane);

    float re[4], im[4];
    re[0] = (lane == 0) ? 1.f : 0.f;
    re[1] = re[2] = re[3] = 0.f;
    im[0] = im[1] = im[2] = im[3] = 0.f;

    const float* xb = x + b * 8;

    // ---- data encoding: RX(x[b,i]) on qubit i (bit 7-i) ----
#define ENC(i) { float s_, c_; __sincosf(xb[i] * 0.5f, &s_, &c_); \
                 apply_rx<7 - (i)>(re, im, lane, px, c_, s_); }
    ENC(0) ENC(1) ENC(2) ENC(3) ENC(4) ENC(5) ENC(6) ENC(7)
#undef ENC

    // ---- variational layers ----
#define VQ(l, i) { const float* g = gc + 2 * ((l) * 24 + (i) * 3); \
                   apply_ry<7 - (i)>(re, im, lane, px, g[0], g[1]); \
                   apply_rz<7 - (i)>(re, im, lane, g[2], g[3]); }
#define CN(i)    apply_cnot<7 - (i), 6 - (i)>(re, im, lane, px);
#define RXQ(l,i) { const float* g = gc + 2 * ((l) * 24 + (i) * 3 + 2); \
                   apply_rx<7 - (i)>(re, im, lane, px, g[0], g[1]); }
#define LAYER(l) \
    VQ(l,0) CN(0) VQ(l,1) CN(1) VQ(l,2) CN(2) VQ(l,3) CN(3) \
    VQ(l,4) CN(4) VQ(l,5) CN(5) VQ(l,6) CN(6) VQ(l,7)       \
    RXQ(l,0) RXQ(l,1) RXQ(l,2) RXQ(l,3) RXQ(l,4) RXQ(l,5) RXQ(l,6) RXQ(l,7)

    LAYER(0)
    LAYER(1)
#undef LAYER
#undef RXQ
#undef CN
#undef VQ

    // ---- <Z_i> readout ----
    float p0 = fmaf(re[0], re[0], im[0] * im[0]);
    float p1 = fmaf(re[1], re[1], im[1] * im[1]);
    float p2 = fmaf(re[2], re[2], im[2] * im[2]);
    float p3 = fmaf(re[3], re[3], im[3] * im[3]);

    float z[8];
    z[0] = (p0 + p1) - (p2 + p3);            // qubit0 = bit7 = k bit1
    z[1] = (p0 - p1) + (p2 - p3);            // qubit1 = bit6 = k bit0
    float pt = (p0 + p1) + (p2 + p3);
#pragma unroll
    for (int i = 2; i < 8; ++i) {            // qubit i = lane bit (7-i)
        int bb = 7 - i;
        z[i] = ((lane >> bb) & 1) ? -pt : pt;
    }

    // wave-wide butterfly sum over all 6 lane bits
#pragma unroll
    for (int i = 0; i < 8; ++i) z[i] += lshfl<0>(z[i], px);
#pragma unroll
    for (int i = 0; i < 8; ++i) z[i] += lshfl<1>(z[i], px);
#pragma unroll
    for (int i = 0; i < 8; ++i) z[i] += lshfl<2>(z[i], px);
#pragma unroll
    for (int i = 0; i < 8; ++i) z[i] += lshfl<3>(z[i], px);
#pragma unroll
    for (int i = 0; i < 8; ++i) z[i] += lshfl<4>(z[i], px);
#pragma unroll
    for (int i = 0; i < 8; ++i) z[i] += lshfl<5>(z[i], px);

    if (lane == 0) {
        float4* o = (float4*)(out + b * 8);
        o[0] = make_float4(z[0], z[1], z[2], z[3]);
        o[1] = make_float4(z[4], z[5], z[6], z[7]);
    }
}

extern "C" void kernel_launch(void* const* d_in, const int* in_sizes, int n_in,
                              void* d_out, int out_size, void* d_ws, size_t ws_size,
                              hipStream_t stream) {
    const float* x      = (const float*)d_in[0];   // (BATCH, 8)
    const float* params = (const float*)d_in[1];   // (2, 8, 3)
    float* out = (float*)d_out;
    float* gc  = (float*)d_ws;                     // 96 floats of (cos,sin)

    int batch   = in_sizes[0] / 8;
    int nparams = in_sizes[1];                     // 48

    qa_prep<<<1, 64, 0, stream>>>(params, gc, nparams);

    int blocks = (batch * 64 + 255) / 256;
    qa_sim<<<blocks, 256, 0, stream>>>(x, gc, out, batch);
}